// Round 13
// baseline (196.682 us; speedup 1.0000x reference)
//
#include <hip/hip_runtime.h>

// HeteroGNN fused implementation, round 13.
// Algebra: new = relu( S @ W1 + deg.*(x @ W2) + x @ W3 + deg.*bmp + bu )
// Round-13: (a) layer-1 gather deleted -- S8 accumulated inside the bucket
// pass (32KB LDS per bucket, bank-rotated fp32 atomics); gemm_l1 is now pure
// streaming; (b) split-column W fragments kill gemm_l1's 4-way LDS conflict
// (5.2M); (c) node-side CSR (offN/adjN) no longer needed by anyone ->
// scan_fill runs link-only. 8 dispatches.

#define H 128
#define NN 50000
#define NL 50000
#define NE 400000
#define NG 64
#define FR 8
#define NB 49          // dst buckets (dst >> 10)
#define BCAP 12288     // entries per bucket (expected ~8163)
#define TSTR 136       // LDS row stride (bf16 elems), layer-2 tile
#define TROWS 32       // layer-2 tile rows

typedef __attribute__((ext_vector_type(8))) short bf16x8;
typedef __attribute__((ext_vector_type(4))) float f32x4;
typedef unsigned short ushort_t;
typedef unsigned int uint_t;

__device__ __forceinline__ ushort_t f2bf(float f) {
    union { float f; unsigned u; } v; v.f = f;
    unsigned r = v.u + 0x7FFFu + ((v.u >> 16) & 1u);   // RNE
    return (ushort_t)(r >> 16);
}
__device__ __forceinline__ float bf2f(ushort_t u) {
    union { unsigned u; float f; } v; v.u = ((unsigned)u) << 16; return v.f;
}
__device__ __forceinline__ void addpk8(float* a, uint4 u) {
    const unsigned* w = (const unsigned*)&u;
#pragma unroll
    for (int q = 0; q < 4; ++q) {
        union { unsigned u; float f; } lo, hi;
        lo.u = w[q] << 16;
        hi.u = w[q] & 0xFFFF0000u;
        a[q * 2 + 0] += lo.f;
        a[q * 2 + 1] += hi.f;
    }
}
__device__ __forceinline__ uint2 pk4(const float* a) {
    uint2 r;
    r.x = (unsigned)f2bf(a[0]) | ((unsigned)f2bf(a[1]) << 16);
    r.y = (unsigned)f2bf(a[2]) | ((unsigned)f2bf(a[3]) << 16);
    return r;
}

// ---------------- weight fusion (+ bf16 per-tile layout for layer-2 link) ----------------
__global__ void precompute_w(const float* __restrict__ Wm_nl, const float* __restrict__ bm_nl,
                             const float* __restrict__ Wu_nl,
                             const float* __restrict__ Wm_ln, const float* __restrict__ bm_ln,
                             const float* __restrict__ Wu_ln,
                             float* __restrict__ Wstack, float* __restrict__ bmp,
                             ushort_t* __restrict__ WbLin) {
    int idx = blockIdx.x * blockDim.x + threadIdx.x;
    const int per = 384 * H + H;
    int c = idx / per, r = idx % per;
    if (c >= 3) return;   // combo 3 (layer-2 node update) is dead code
    int l = c >> 1, rel = c & 1;
    const float* Wm = (rel ? Wm_ln : Wm_nl) + l * 256 * H;
    const float* Wu = (rel ? Wu_ln : Wu_nl) + l * 256 * H;
    const float* bm = (rel ? bm_ln : bm_nl) + l * H;
    float* Ws = Wstack + c * 384 * H;
    if (r < 384 * H) {
        int t = r / H, j = r % H;
        float val;
        if (t < 256) {
            float acc = 0.f;
            for (int k = 0; k < H; ++k) acc += Wm[t * H + k] * Wu[k * H + j];
            val = acc;
        } else {
            val = Wu[(t - 128) * H + j];
        }
        Ws[t * H + j] = val;
        if (c == 2) {
            WbLin[(size_t)(t >> 5) * 4096 + j * 32 + (t & 31)] = f2bf(val);
        }
    } else {
        int j = r - 384 * H;
        float acc = 0.f;
        for (int k = 0; k < H; ++k) acc += bm[k] * Wu[k * H + j];
        bmp[c * H + j] = acc;
    }
}

// ---------------- pass A: bucket-scatter edges by dst ----------------
__launch_bounds__(256)
__global__ void bucket_scatter(const int* __restrict__ nl, const int* __restrict__ ln,
                               uint_t* __restrict__ bbuf, int* __restrict__ gcount) {
    int rel = blockIdx.y;
    const int* edge = rel ? ln : nl;
    uint_t* bb = bbuf + (size_t)rel * NB * BCAP;
    int* gc = gcount + rel * NB;
    __shared__ int hist[NB], base[NB], cur[NB];
    int tid = threadIdx.x;
    if (tid < NB) hist[tid] = 0;
    __syncthreads();
    int e0 = blockIdx.x * 2048 + tid;
    int src[8], dst[8];
#pragma unroll
    for (int i = 0; i < 8; ++i) {
        int e = e0 + i * 256;
        if (e < NE) {
            src[i] = edge[e];
            dst[i] = edge[NE + e];
            atomicAdd(&hist[dst[i] >> 10], 1);
        } else dst[i] = -1;
    }
    __syncthreads();
    if (tid < NB) { base[tid] = atomicAdd(&gc[tid], hist[tid]); cur[tid] = 0; }
    __syncthreads();
#pragma unroll
    for (int i = 0; i < 8; ++i) {
        if (dst[i] >= 0) {
            int b = dst[i] >> 10;
            int p = base[b] + atomicAdd(&cur[b], 1);
            bb[(size_t)b * BCAP + p] = (uint_t)src[i] | ((uint_t)(dst[i] & 1023) << 16);
        }
    }
}

// ---------------- pass B: per-bucket degree + S8 accumulation (+ gcount scan in block NB) ----------------
// s8 LDS layout is bank-rotated: col c of dst i lives at s8[i][(c+i)&7],
// spreading the 8-col atomics across all 32 banks (naive layout = 16-way).
__launch_bounds__(256)
__global__ void bucket_deg_s8(const uint_t* __restrict__ bbuf, const int* __restrict__ gcount,
                              const float* __restrict__ x_node, const float* __restrict__ x_link,
                              int* __restrict__ idl,
                              float* __restrict__ fdegL, float* __restrict__ fdegN,
                              float* __restrict__ S8l, float* __restrict__ S8n,
                              int* __restrict__ bbase) {
    int rel = blockIdx.y, b = blockIdx.x;
    int tid = threadIdx.x;
    if (b == NB) {
        // exclusive scan of gcount[rel*NB .. +NB)  (only rel=0 consumed, cheap)
        __shared__ int sh[64];
        int v0 = 0;
        if (tid < 64) { v0 = (tid < NB) ? gcount[rel * NB + tid] : 0; sh[tid] = v0; }
        __syncthreads();
        for (int d = 1; d < 64; d <<= 1) {
            int vv = (tid >= d && tid < 64) ? sh[tid - d] : 0;
            __syncthreads();
            if (tid < 64) sh[tid] += vv;
            __syncthreads();
        }
        if (tid < NB) bbase[rel * NB + tid] = sh[tid] - v0;
        return;
    }
    const uint_t* bb = bbuf + ((size_t)rel * NB + b) * BCAP;
    int n = gcount[rel * NB + b];
    const float* Xr = rel ? x_link : x_node;     // gather source (src-type raw features)
    float* fdeg = rel ? fdegN : fdegL;
    float* S8 = rel ? S8n : S8l;

    __shared__ int ld[1024];
    __shared__ float s8[1024][8];                // 32 KB
    for (int i = tid; i < 1024; i += 256) {
        ld[i] = 0;
        *(float4*)&s8[i][0] = make_float4(0.f, 0.f, 0.f, 0.f);
        *(float4*)&s8[i][4] = make_float4(0.f, 0.f, 0.f, 0.f);
    }
    __syncthreads();

    // 2-unrolled entry loop for MLP
    for (int i = tid; i < n; i += 512) {
        uint_t v0 = bb[i];
        int i2 = i + 256;
        uint_t v1 = (i2 < n) ? bb[i2] : 0u;
        int d0 = v0 >> 16, s0 = (int)(v0 & 0xFFFFu);
        float4 a0 = *(const float4*)(Xr + (size_t)s0 * FR);
        float4 a1 = *(const float4*)(Xr + (size_t)s0 * FR + 4);
        float4 b0 = make_float4(0.f, 0.f, 0.f, 0.f), b1 = b0;
        int d1 = 0;
        if (i2 < n) {
            d1 = v1 >> 16;
            int s1 = (int)(v1 & 0xFFFFu);
            b0 = *(const float4*)(Xr + (size_t)s1 * FR);
            b1 = *(const float4*)(Xr + (size_t)s1 * FR + 4);
        }
        atomicAdd(&ld[d0], 1);
        float fa[8] = {a0.x, a0.y, a0.z, a0.w, a1.x, a1.y, a1.z, a1.w};
#pragma unroll
        for (int c = 0; c < 8; ++c)
            atomicAdd(&s8[d0][(c + d0) & 7], fa[c]);
        if (i2 < n) {
            atomicAdd(&ld[d1], 1);
            float fb[8] = {b0.x, b0.y, b0.z, b0.w, b1.x, b1.y, b1.z, b1.w};
#pragma unroll
            for (int c = 0; c < 8; ++c)
                atomicAdd(&s8[d1][(c + d1) & 7], fb[c]);
        }
    }
    __syncthreads();

    int dbase = b << 10;
    for (int i = tid; i < 1024; i += 256) {
        int d = dbase + i;
        if (d < NL) {
            fdeg[d] = (float)ld[i];
            if (rel == 0) idl[d] = ld[i];
            float o[8];
#pragma unroll
            for (int c = 0; c < 8; ++c) o[c] = s8[i][(c + i) & 7];
            *(float4*)(S8 + (size_t)d * FR)     = *(float4*)(o);
            *(float4*)(S8 + (size_t)d * FR + 4) = *(float4*)(o + 4);
        }
    }
}

// ---------------- pass C: link-only offset scan + CSR fill ----------------
__launch_bounds__(256)
__global__ void scan_fill(const int* __restrict__ degL, const int* __restrict__ bbase,
                          int* __restrict__ offL,
                          const uint_t* __restrict__ bbuf, const int* __restrict__ gcount,
                          int* __restrict__ adjL) {
    int blk = blockIdx.x;
    const uint_t* bb = bbuf + (size_t)blk * BCAP;   // rel 0 buckets
    int n = gcount[blk];

    __shared__ int part[256];
    __shared__ int lcur[1024];
    int tid = threadIdx.x;
    int base = blk * 1024 + tid * 4;
    int d4[4]; int s = 0;
#pragma unroll
    for (int i = 0; i < 4; ++i) {
        int idx = base + i;
        d4[i] = (idx < NL) ? degL[idx] : 0;
        s += d4[i];
    }
    part[tid] = s;
    __syncthreads();
    for (int d = 1; d < 256; d <<= 1) {
        int v = (tid >= d) ? part[tid - d] : 0;
        __syncthreads();
        part[tid] += v;
        __syncthreads();
    }
    int run = bbase[blk] + part[tid] - s;
#pragma unroll
    for (int i = 0; i < 4; ++i) {
        int idx = base + i;
        lcur[tid * 4 + i] = run;
        if (idx < NL) {
            offL[idx] = run;
            run += d4[i];
            if (idx == NL - 1) offL[NL] = run;
        }
    }
    __syncthreads();
    for (int i = tid; i < n; i += 256) {
        uint_t v = bb[i];
        int p = atomicAdd(&lcur[v >> 16], 1);
        adjL[p] = (int)(v & 0xFFFFu);
    }
}

// ---------------- layer-1: streaming GEMM (K=24), bf16 out ----------------
// a = [S8 | deg*Xo | Xo]; split-column fragments (c0=t16*4, c1=64+t16*4)
// make the Wl reads 2-way (free) instead of 4-way conflicted.
__launch_bounds__(256)
__global__ void gemm_l1(const float* __restrict__ S8l, const float* __restrict__ S8n,
                        const float* __restrict__ x_node, const float* __restrict__ x_link,
                        const float* __restrict__ dgl, const float* __restrict__ dgn,
                        const float* __restrict__ Wstack, const float* __restrict__ bmpAll,
                        const float* __restrict__ bu_nl, const float* __restrict__ bu_ln,
                        ushort_t* __restrict__ outl, ushort_t* __restrict__ outn) {
    int rel = blockIdx.y;
    const float* S8  = rel ? S8n : S8l;
    const float* Xo  = rel ? x_node : x_link;   // own raw features
    const float* deg = rel ? dgn : dgl;
    const float* Ws  = Wstack + (size_t)rel * 384 * H;
    const float* bmp = bmpAll + rel * H;
    const float* bu  = rel ? bu_ln : bu_nl;
    ushort_t* Out = rel ? outn : outl;

    __shared__ float Wl[24][H];
    __shared__ float bf2s[2][H];
    int tid = threadIdx.x;
    for (int p = tid; p < 24 * H; p += 256) {
        int kk = p >> 7, c = p & 127;
        int srcrow = (kk >> 3) * 128 + (kk & 7);
        Wl[kk][c] = Ws[srcrow * H + c];
    }
    if (tid < 128) { bf2s[0][tid] = bmp[tid]; bf2s[1][tid] = bu[tid]; }
    __syncthreads();

    int rl = tid >> 4, t16 = tid & 15;
    int row = blockIdx.x * 16 + rl;              // grid 3125 -> exact
    float d = deg[row];
    float a[16];
    *(float4*)(a)      = *(const float4*)(S8 + (size_t)row * FR);
    *(float4*)(a + 4)  = *(const float4*)(S8 + (size_t)row * FR + 4);
    *(float4*)(a + 8)  = *(const float4*)(Xo + (size_t)row * FR);
    *(float4*)(a + 12) = *(const float4*)(Xo + (size_t)row * FR + 4);

    int c0 = t16 * 4, c1 = 64 + t16 * 4;
    float acc[8] = {};
#pragma unroll
    for (int k = 0; k < 8; ++k) {
        float4 w0 = *(const float4*)(&Wl[k][c0]);
        float4 w1 = *(const float4*)(&Wl[k][c1]);
        float av = a[k];
        acc[0] += av * w0.x; acc[1] += av * w0.y; acc[2] += av * w0.z; acc[3] += av * w0.w;
        acc[4] += av * w1.x; acc[5] += av * w1.y; acc[6] += av * w1.z; acc[7] += av * w1.w;
    }
#pragma unroll
    for (int k = 0; k < 8; ++k) {
        float4 w0 = *(const float4*)(&Wl[8 + k][c0]);
        float4 w1 = *(const float4*)(&Wl[8 + k][c1]);
        float av = d * a[8 + k];
        acc[0] += av * w0.x; acc[1] += av * w0.y; acc[2] += av * w0.z; acc[3] += av * w0.w;
        acc[4] += av * w1.x; acc[5] += av * w1.y; acc[6] += av * w1.z; acc[7] += av * w1.w;
    }
#pragma unroll
    for (int k = 0; k < 8; ++k) {
        float4 w0 = *(const float4*)(&Wl[16 + k][c0]);
        float4 w1 = *(const float4*)(&Wl[16 + k][c1]);
        float av = a[8 + k];
        acc[0] += av * w0.x; acc[1] += av * w0.y; acc[2] += av * w0.z; acc[3] += av * w0.w;
        acc[4] += av * w1.x; acc[5] += av * w1.y; acc[6] += av * w1.z; acc[7] += av * w1.w;
    }

    float o0[4], o1[4];
#pragma unroll
    for (int j = 0; j < 4; ++j) {
        o0[j] = fmaxf(acc[j]     + d * bf2s[0][c0 + j] + bf2s[1][c0 + j], 0.f);
        o1[j] = fmaxf(acc[j + 4] + d * bf2s[0][c1 + j] + bf2s[1][c1 + j], 0.f);
    }
    *(uint2*)(Out + (size_t)row * H + c0) = pk4(o0);
    *(uint2*)(Out + (size_t)row * H + c1) = pk4(o1);
}

// ---------------- layer-2: fused gather + MFMA GEMM + pooled epilogue (link only) ----------------
__launch_bounds__(256)
__global__ void gemm_mfma_pool(const int* __restrict__ offL, const int* __restrict__ adjL,
                               const ushort_t* __restrict__ xlb, const ushort_t* __restrict__ xnb,
                               const float* __restrict__ dgl,
                               const ushort_t* __restrict__ WbLin, const float* __restrict__ bmpAll,
                               const float* __restrict__ bu_nl,
                               const int* __restrict__ batch, float* __restrict__ sums, int M) {
    const int* off = offL;
    const int* adj = adjL;
    const ushort_t* Xg = xnb;
    const ushort_t* Xo = xlb;
    const float* deg = dgl;
    const ushort_t* Wb = WbLin;
    const float* bmp = bmpAll + 2 * H;
    const float* bu  = bu_nl + H;

    __shared__ ushort_t T[TROWS * TSTR];   // 8.7 KB

    int tid = threadIdx.x;
    int lane = tid & 63;
    int wave = tid >> 6;
    int m0 = blockIdx.x * TROWS;
    int lrow = lane & 15, lg = lane >> 4;

    int trow = tid >> 3, chunk = tid & 7;
    int grow = m0 + trow;
    bool vr = grow < M;
    int cbase = chunk * 16;

    // ---- phase A: gather S (fp32 accum, 2-neighbor unroll) -> bf16 tile ----
    {
        float a[16];
#pragma unroll
        for (int j = 0; j < 16; ++j) a[j] = 0.f;
        if (vr) {
            int beg = off[grow], end = off[grow + 1];
            int i = beg;
            for (; i + 1 < end; i += 2) {
                const uint4* p0 = (const uint4*)(Xg + (size_t)adj[i] * H + cbase);
                const uint4* p1 = (const uint4*)(Xg + (size_t)adj[i + 1] * H + cbase);
                uint4 u0 = p0[0], u1 = p0[1];
                uint4 v0 = p1[0], v1 = p1[1];
                addpk8(a, u0); addpk8(a + 8, u1);
                addpk8(a, v0); addpk8(a + 8, v1);
            }
            if (i < end) {
                const uint4* p0 = (const uint4*)(Xg + (size_t)adj[i] * H + cbase);
                addpk8(a, p0[0]); addpk8(a + 8, p0[1]);
            }
        }
        uint4* dst = (uint4*)&T[trow * TSTR + cbase];
        uint4 w0, w1;
        unsigned* q0 = (unsigned*)&w0; unsigned* q1 = (unsigned*)&w1;
#pragma unroll
        for (int q = 0; q < 4; ++q) {
            q0[q] = (unsigned)f2bf(a[q * 2]) | ((unsigned)f2bf(a[q * 2 + 1]) << 16);
            q1[q] = (unsigned)f2bf(a[8 + q * 2]) | ((unsigned)f2bf(a[8 + q * 2 + 1]) << 16);
        }
        dst[0] = w0; dst[1] = w1;
    }

    f32x4 acc[2][2];
#pragma unroll
    for (int i = 0; i < 2; ++i)
#pragma unroll
        for (int j = 0; j < 2; ++j)
            acc[i][j] = (f32x4){0.f, 0.f, 0.f, 0.f};

    __syncthreads();
#pragma unroll
    for (int kk = 0; kk < 4; ++kk) {
        bf16x8 af[2], bfv[2];
#pragma unroll
        for (int mf = 0; mf < 2; ++mf)
            af[mf] = *(const bf16x8*)&T[(mf * 16 + lrow) * TSTR + kk * 32 + lg * 8];
#pragma unroll
        for (int nf = 0; nf < 2; ++nf)
            bfv[nf] = *(const bf16x8*)(Wb + (size_t)kk * 4096
                        + (wave * 32 + nf * 16 + lrow) * 32 + lg * 8);
#pragma unroll
        for (int mf = 0; mf < 2; ++mf)
#pragma unroll
            for (int nf = 0; nf < 2; ++nf)
                acc[mf][nf] = __builtin_amdgcn_mfma_f32_16x16x32_bf16(
                    af[mf], bfv[nf], acc[mf][nf], 0, 0, 0);
    }
    __syncthreads();

    // ---- phase B: own x row (stash) -> deg-scaled tile ----
    uint4 xs0, xs1;
    {
        if (vr) {
            const uint4* p = (const uint4*)(Xo + (size_t)grow * H + cbase);
            xs0 = p[0]; xs1 = p[1];
        } else {
            xs0 = xs1 = make_uint4(0u, 0u, 0u, 0u);
        }
        float dr = vr ? deg[grow] : 0.f;
        uint4 w0 = xs0, w1 = xs1;
        unsigned* wp0 = (unsigned*)&w0;
        unsigned* wp1 = (unsigned*)&w1;
#pragma unroll
        for (int q = 0; q < 4; ++q) {
            float v0 = dr * bf2f((ushort_t)(wp0[q] & 0xFFFF));
            float v1 = dr * bf2f((ushort_t)(wp0[q] >> 16));
            wp0[q] = (unsigned)f2bf(v0) | ((unsigned)f2bf(v1) << 16);
            float v2 = dr * bf2f((ushort_t)(wp1[q] & 0xFFFF));
            float v3 = dr * bf2f((ushort_t)(wp1[q] >> 16));
            wp1[q] = (unsigned)f2bf(v2) | ((unsigned)f2bf(v3) << 16);
        }
        uint4* dst = (uint4*)&T[trow * TSTR + cbase];
        dst[0] = w0; dst[1] = w1;
    }
    __syncthreads();
#pragma unroll
    for (int kk = 0; kk < 4; ++kk) {
        bf16x8 af[2], bfv[2];
#pragma unroll
        for (int mf = 0; mf < 2; ++mf)
            af[mf] = *(const bf16x8*)&T[(mf * 16 + lrow) * TSTR + kk * 32 + lg * 8];
#pragma unroll
        for (int nf = 0; nf < 2; ++nf)
            bfv[nf] = *(const bf16x8*)(Wb + (size_t)(4 + kk) * 4096
                        + (wave * 32 + nf * 16 + lrow) * 32 + lg * 8);
#pragma unroll
        for (int mf = 0; mf < 2; ++mf)
#pragma unroll
            for (int nf = 0; nf < 2; ++nf)
                acc[mf][nf] = __builtin_amdgcn_mfma_f32_16x16x32_bf16(
                    af[mf], bfv[nf], acc[mf][nf], 0, 0, 0);
    }
    __syncthreads();

    // ---- phase C: unscaled x tile (from stash) ----
    {
        uint4* dst = (uint4*)&T[trow * TSTR + cbase];
        dst[0] = xs0; dst[1] = xs1;
    }
    __syncthreads();
#pragma unroll
    for (int kk = 0; kk < 4; ++kk) {
        bf16x8 af[2], bfv[2];
#pragma unroll
        for (int mf = 0; mf < 2; ++mf)
            af[mf] = *(const bf16x8*)&T[(mf * 16 + lrow) * TSTR + kk * 32 + lg * 8];
#pragma unroll
        for (int nf = 0; nf < 2; ++nf)
            bfv[nf] = *(const bf16x8*)(Wb + (size_t)(8 + kk) * 4096
                        + (wave * 32 + nf * 16 + lrow) * 32 + lg * 8);
#pragma unroll
        for (int mf = 0; mf < 2; ++mf)
#pragma unroll
            for (int nf = 0; nf < 2; ++nf)
                acc[mf][nf] = __builtin_amdgcn_mfma_f32_16x16x32_bf16(
                    af[mf], bfv[nf], acc[mf][nf], 0, 0, 0);
    }

    // ---- epilogue: bias + relu + fused mean-pool ----
    float bmpv[2], buv[2];
#pragma unroll
    for (int nf = 0; nf < 2; ++nf) {
        int col = wave * 32 + nf * 16 + lrow;
        bmpv[nf] = bmp[col];
        buv[nf] = bu[col];
    }
    int lastrow = min(m0 + TROWS, M) - 1;
    int g0 = batch[m0];
    int g1 = batch[lastrow];
    if (g0 == g1) {
        float ps0 = 0.f, ps1 = 0.f;
#pragma unroll
        for (int mf = 0; mf < 2; ++mf) {
#pragma unroll
            for (int r = 0; r < 4; ++r) {
                int row = m0 + mf * 16 + lg * 4 + r;
                if (row < M) {
                    float d = deg[row];
                    ps0 += fmaxf(acc[mf][0][r] + d * bmpv[0] + buv[0], 0.f);
                    ps1 += fmaxf(acc[mf][1][r] + d * bmpv[1] + buv[1], 0.f);
                }
            }
        }
        ps0 += __shfl_xor(ps0, 16); ps0 += __shfl_xor(ps0, 32);
        ps1 += __shfl_xor(ps1, 16); ps1 += __shfl_xor(ps1, 32);
        if (lg == 0) {
            atomicAdd(&sums[g0 * H + wave * 32 + lrow], ps0);
            atomicAdd(&sums[g0 * H + wave * 32 + 16 + lrow], ps1);
        }
    } else {
#pragma unroll
        for (int mf = 0; mf < 2; ++mf) {
#pragma unroll
            for (int r = 0; r < 4; ++r) {
                int row = m0 + mf * 16 + lg * 4 + r;
                if (row < M) {
                    float d = deg[row];
                    int g = batch[row];
                    float v0 = fmaxf(acc[mf][0][r] + d * bmpv[0] + buv[0], 0.f);
                    float v1 = fmaxf(acc[mf][1][r] + d * bmpv[1] + buv[1], 0.f);
                    atomicAdd(&sums[g * H + wave * 32 + lrow], v0);
                    atomicAdd(&sums[g * H + wave * 32 + 16 + lrow], v1);
                }
            }
        }
    }
}

// ---------------- pool finalize (counts via binary search) ----------------
__global__ void pool_final(const float* __restrict__ sums, const int* __restrict__ batch,
                           float* __restrict__ out) {
    int idx = blockIdx.x * blockDim.x + threadIdx.x;
    int g = idx / H;
    int lo = 0, hi = NL;
    while (lo < hi) { int mid = (lo + hi) >> 1; if (batch[mid] < g) lo = mid + 1; else hi = mid; }
    int first = lo;
    lo = 0; hi = NL;
    while (lo < hi) { int mid = (lo + hi) >> 1; if (batch[mid] < g + 1) lo = mid + 1; else hi = mid; }
    float cnt = (float)(lo - first);
    out[idx] = sums[idx] / fmaxf(cnt, 1.f);
}

static inline size_t rup(size_t n) { return (n + 15) & ~(size_t)15; }

extern "C" void kernel_launch(void* const* d_in, const int* in_sizes, int n_in,
                              void* d_out, int out_size, void* d_ws, size_t ws_size,
                              hipStream_t stream) {
    const float* x_node = (const float*)d_in[0];
    const float* x_link = (const float*)d_in[1];
    const float* Wm_nl  = (const float*)d_in[2];
    const float* bm_nl  = (const float*)d_in[3];
    const float* Wu_nl  = (const float*)d_in[4];
    const float* bu_nl  = (const float*)d_in[5];
    const float* Wm_ln  = (const float*)d_in[6];
    const float* bm_ln  = (const float*)d_in[7];
    const float* Wu_ln  = (const float*)d_in[8];
    const float* bu_ln  = (const float*)d_in[9];
    const int* nl_edge  = (const int*)d_in[10];
    const int* ln_edge  = (const int*)d_in[11];
    const int* batch_link = (const int*)d_in[12];
    (void)in_sizes; (void)n_in; (void)out_size; (void)ws_size;

    char* wsb = (char*)d_ws;
    size_t o = 0;
    auto alloc = [&](size_t elems) { void* p = wsb + o * 4; o += rup(elems); return p; };
    ushort_t* xnb  = (ushort_t*)alloc((size_t)NN * H / 2);
    ushort_t* xlb  = (ushort_t*)alloc((size_t)NL * H / 2);
    float* S8l   = (float*)alloc((size_t)NL * FR);
    float* S8n   = (float*)alloc((size_t)NN * FR);
    float* deg_l = (float*)alloc(NL);
    float* deg_n = (float*)alloc(NN);
    int*   idl   = (int*)alloc(NL);
    int*   offL  = (int*)alloc(NL + 1);
    int*   adjL  = (int*)alloc(NE);
    float* Wstack= (float*)alloc(3L * 384 * H);
    float* bmp   = (float*)alloc(4 * H);
    ushort_t* WbLin = (ushort_t*)alloc(12 * 4096 / 2);
    uint_t* bbuf  = (uint_t*)alloc((size_t)2 * NB * BCAP);
    int*   bbase = (int*)alloc(2 * NB);
    float* sums  = (float*)alloc(NG * H);    // NG*H = 8192 (16-aligned)
    int*   gcount= (int*)alloc(2 * NB);      // contiguous after sums -> one memset

    hipMemsetAsync(sums, 0, ((size_t)NG * H + rup(2 * NB)) * 4, stream);

    precompute_w<<<(4 * (384 * H + H) + 255) / 256, 256, 0, stream>>>(
        Wm_nl, bm_nl, Wu_nl, Wm_ln, bm_ln, Wu_ln, Wstack, bmp, WbLin);

    // ---- CSR build + fused S8/deg ----
    bucket_scatter<<<dim3((NE + 2047) / 2048, 2), 256, 0, stream>>>(
        nl_edge, ln_edge, bbuf, gcount);
    bucket_deg_s8<<<dim3(NB + 1, 2), 256, 0, stream>>>(
        bbuf, gcount, x_node, x_link, idl, deg_l, deg_n, S8l, S8n, bbase);
    scan_fill<<<NB, 256, 0, stream>>>(idl, bbase, offL, bbuf, gcount, adjL);

    // ---- layer 1 (streaming GEMM, both relations) ----
    gemm_l1<<<dim3(NL / 16, 2), 256, 0, stream>>>(
        S8l, S8n, x_node, x_link, deg_l, deg_n,
        Wstack, bmp, bu_nl, bu_ln, xlb, xnb);

    // ---- layer 2 (link only) + fused pool ----
    gemm_mfma_pool<<<(NL + TROWS - 1) / TROWS, 256, 0, stream>>>(
        offL, adjL, xlb, xnb, deg_l, WbLin, bmp, bu_nl,
        batch_link, sums, NL);

    pool_final<<<(NG * H) / 256, 256, 0, stream>>>(sums, batch_link, (float*)d_out);
}

// Round 15
// 141.569 us; speedup vs baseline: 1.3893x; 1.3893x over previous
//
#include <hip/hip_runtime.h>

// HeteroGNN fused implementation, round 15.
// Algebra: new = relu( S @ W1 + deg.*(x @ W2) + x @ W3 + deg.*bmp + bu )
// Round-15: r14 staging-predicate BUGFIX -- xo staging used tid in [160,288)
// but the block has 256 threads, leaving rows 12..15 unstaged (absmax 0.13).
// All small stages now sit on low tids with overlapping predicates.
// Otherwise identical to r14 (coalesced adj staging, 2x4 micro-tile).

#define H 128
#define NN 50000
#define NL 50000
#define NE 400000
#define NG 64
#define FR 8
#define NB 49          // dst buckets (dst >> 10)
#define BCAP 12288     // entries per bucket (expected ~8163)
#define TSTR 136       // LDS row stride (bf16 elems), layer-2 tile
#define TROWS 32       // layer-2 tile rows
#define L1R 16         // layer-1 rows per block
#define AMAX 448       // adjacency staging capacity (avg 128, tail-safe)

typedef __attribute__((ext_vector_type(8))) short bf16x8;
typedef __attribute__((ext_vector_type(4))) float f32x4;
typedef unsigned short ushort_t;
typedef unsigned int uint_t;

__device__ __forceinline__ ushort_t f2bf(float f) {
    union { float f; unsigned u; } v; v.f = f;
    unsigned r = v.u + 0x7FFFu + ((v.u >> 16) & 1u);   // RNE
    return (ushort_t)(r >> 16);
}
__device__ __forceinline__ float bf2f(ushort_t u) {
    union { unsigned u; float f; } v; v.u = ((unsigned)u) << 16; return v.f;
}
__device__ __forceinline__ void addpk8(float* a, uint4 u) {
    const unsigned* w = (const unsigned*)&u;
#pragma unroll
    for (int q = 0; q < 4; ++q) {
        union { unsigned u; float f; } lo, hi;
        lo.u = w[q] << 16;
        hi.u = w[q] & 0xFFFF0000u;
        a[q * 2 + 0] += lo.f;
        a[q * 2 + 1] += hi.f;
    }
}
__device__ __forceinline__ uint2 pk4(const float* a) {
    uint2 r;
    r.x = (unsigned)f2bf(a[0]) | ((unsigned)f2bf(a[1]) << 16);
    r.y = (unsigned)f2bf(a[2]) | ((unsigned)f2bf(a[3]) << 16);
    return r;
}

// ---------------- weight fusion (+ bf16 per-tile layout for layer-2 link) ----------------
__global__ void precompute_w(const float* __restrict__ Wm_nl, const float* __restrict__ bm_nl,
                             const float* __restrict__ Wu_nl,
                             const float* __restrict__ Wm_ln, const float* __restrict__ bm_ln,
                             const float* __restrict__ Wu_ln,
                             float* __restrict__ Wstack, float* __restrict__ bmp,
                             ushort_t* __restrict__ WbLin) {
    int idx = blockIdx.x * blockDim.x + threadIdx.x;
    const int per = 384 * H + H;
    int c = idx / per, r = idx % per;
    if (c >= 3) return;   // combo 3 (layer-2 node update) is dead code
    int l = c >> 1, rel = c & 1;
    const float* Wm = (rel ? Wm_ln : Wm_nl) + l * 256 * H;
    const float* Wu = (rel ? Wu_ln : Wu_nl) + l * 256 * H;
    const float* bm = (rel ? bm_ln : bm_nl) + l * H;
    float* Ws = Wstack + c * 384 * H;
    if (r < 384 * H) {
        int t = r / H, j = r % H;
        float val;
        if (t < 256) {
            float acc = 0.f;
            for (int k = 0; k < H; ++k) acc += Wm[t * H + k] * Wu[k * H + j];
            val = acc;
        } else {
            val = Wu[(t - 128) * H + j];
        }
        Ws[t * H + j] = val;
        if (c == 2) {
            WbLin[(size_t)(t >> 5) * 4096 + j * 32 + (t & 31)] = f2bf(val);
        }
    } else {
        int j = r - 384 * H;
        float acc = 0.f;
        for (int k = 0; k < H; ++k) acc += bm[k] * Wu[k * H + j];
        bmp[c * H + j] = acc;
    }
}

// ---------------- pass A: bucket-scatter edges by dst ----------------
__launch_bounds__(256)
__global__ void bucket_scatter(const int* __restrict__ nl, const int* __restrict__ ln,
                               uint_t* __restrict__ bbuf, int* __restrict__ gcount) {
    int rel = blockIdx.y;
    const int* edge = rel ? ln : nl;
    uint_t* bb = bbuf + (size_t)rel * NB * BCAP;
    int* gc = gcount + rel * NB;
    __shared__ int hist[NB], base[NB], cur[NB];
    int tid = threadIdx.x;
    if (tid < NB) hist[tid] = 0;
    __syncthreads();
    int e0 = blockIdx.x * 2048 + tid;
    int src[8], dst[8];
#pragma unroll
    for (int i = 0; i < 8; ++i) {
        int e = e0 + i * 256;
        if (e < NE) {
            src[i] = edge[e];
            dst[i] = edge[NE + e];
            atomicAdd(&hist[dst[i] >> 10], 1);
        } else dst[i] = -1;
    }
    __syncthreads();
    if (tid < NB) { base[tid] = atomicAdd(&gc[tid], hist[tid]); cur[tid] = 0; }
    __syncthreads();
#pragma unroll
    for (int i = 0; i < 8; ++i) {
        if (dst[i] >= 0) {
            int b = dst[i] >> 10;
            int p = base[b] + atomicAdd(&cur[b], 1);
            bb[(size_t)b * BCAP + p] = (uint_t)src[i] | ((uint_t)(dst[i] & 1023) << 16);
        }
    }
}

// ---------------- pass B: per-bucket degree + gcount scan (block NB) ----------------
__launch_bounds__(256)
__global__ void bucket_deg2(const uint_t* __restrict__ bbuf, const int* __restrict__ gcount,
                            int* __restrict__ degL, int* __restrict__ degN,
                            int* __restrict__ bbase) {
    int rel = blockIdx.y, b = blockIdx.x;
    int tid = threadIdx.x;
    if (b == NB) {
        __shared__ int sh[64];
        int v0 = 0;
        if (tid < 64) { v0 = (tid < NB) ? gcount[rel * NB + tid] : 0; sh[tid] = v0; }
        __syncthreads();
        for (int d = 1; d < 64; d <<= 1) {
            int vv = (tid >= d && tid < 64) ? sh[tid - d] : 0;
            __syncthreads();
            if (tid < 64) sh[tid] += vv;
            __syncthreads();
        }
        if (tid < NB) bbase[rel * NB + tid] = sh[tid] - v0;
        return;
    }
    const uint_t* bb = bbuf + ((size_t)rel * NB + b) * BCAP;
    int n = gcount[rel * NB + b];
    int* deg = rel ? degN : degL;
    __shared__ int ld[1024];
    for (int i = tid; i < 1024; i += 256) ld[i] = 0;
    __syncthreads();
    for (int i = tid; i < n; i += 256) atomicAdd(&ld[bb[i] >> 16], 1);
    __syncthreads();
    int dbase = b << 10;
    for (int i = tid; i < 1024; i += 256) {
        int d = dbase + i;
        if (d < NL) deg[d] = ld[i];
    }
}

// ---------------- pass C: per-bucket offset scan + CSR fill (fused, both relations) ----------------
__launch_bounds__(256)
__global__ void scan_fill(const int* __restrict__ degL, const int* __restrict__ degN,
                          const int* __restrict__ bbase,
                          int* __restrict__ offL, int* __restrict__ offN,
                          float* __restrict__ fdegL, float* __restrict__ fdegN,
                          const uint_t* __restrict__ bbuf, const int* __restrict__ gcount,
                          int* __restrict__ adjL, int* __restrict__ adjN) {
    int arr = blockIdx.y, blk = blockIdx.x;
    const int* deg = arr ? degN : degL;
    int* off = arr ? offN : offL;
    float* fdeg = arr ? fdegN : fdegL;
    int* adj = arr ? adjN : adjL;
    const uint_t* bb = bbuf + ((size_t)arr * NB + blk) * BCAP;
    int n = gcount[arr * NB + blk];

    __shared__ int part[256];
    __shared__ int lcur[1024];
    int tid = threadIdx.x;
    int base = blk * 1024 + tid * 4;
    int d4[4]; int s = 0;
#pragma unroll
    for (int i = 0; i < 4; ++i) {
        int idx = base + i;
        d4[i] = (idx < NL) ? deg[idx] : 0;
        s += d4[i];
    }
    part[tid] = s;
    __syncthreads();
    for (int d = 1; d < 256; d <<= 1) {
        int v = (tid >= d) ? part[tid - d] : 0;
        __syncthreads();
        part[tid] += v;
        __syncthreads();
    }
    int run = bbase[arr * NB + blk] + part[tid] - s;
#pragma unroll
    for (int i = 0; i < 4; ++i) {
        int idx = base + i;
        lcur[tid * 4 + i] = run;
        if (idx < NL) {
            off[idx] = run; fdeg[idx] = (float)d4[i];
            run += d4[i];
            if (idx == NL - 1) off[NL] = run;
        }
    }
    __syncthreads();
    for (int i = tid; i < n; i += 256) {
        uint_t v = bb[i];
        int p = atomicAdd(&lcur[v >> 16], 1);
        adj[p] = (int)(v & 0xFFFFu);
    }
}

// ---------------- layer-1: fused gather + GEMM (K=24), bf16 out ----------------
__launch_bounds__(256)
__global__ void gemm_l1_f(const int* __restrict__ offL, const int* __restrict__ adjL,
                          const int* __restrict__ offN, const int* __restrict__ adjN,
                          const float* __restrict__ x_node, const float* __restrict__ x_link,
                          const float* __restrict__ dgl, const float* __restrict__ dgn,
                          const float* __restrict__ Wstack, const float* __restrict__ bmpAll,
                          const float* __restrict__ bu_nl, const float* __restrict__ bu_ln,
                          ushort_t* __restrict__ outl, ushort_t* __restrict__ outn) {
    int rel = blockIdx.y;
    const int* off = rel ? offN : offL;
    const int* adj = rel ? adjN : adjL;
    const float* Xg = rel ? x_link : x_node;   // gather source (opposite type, raw)
    const float* Xo = rel ? x_node : x_link;   // own raw features
    const float* deg = rel ? dgn : dgl;
    const float* Ws  = Wstack + (size_t)rel * 384 * H;
    const float* bmp = bmpAll + rel * H;
    const float* bu  = rel ? bu_ln : bu_nl;
    ushort_t* Out = rel ? outn : outl;

    __shared__ float Wl[24][H];        // 12 KB
    __shared__ float bf2s[2][H];       // 1 KB
    __shared__ float G[L1R][2][8];     // 1 KB
    __shared__ float S8r[L1R][8];      // 0.5 KB
    __shared__ float xo[L1R][8];       // 0.5 KB
    __shared__ int   aoff[L1R + 1];
    __shared__ int   abuf[AMAX];       // 1.75 KB

    int tid = threadIdx.x;
    int r0 = blockIdx.x * L1R;

    // phase 1: stage W, biases, offsets, own-feature rows
    // (predicates overlap -- a low-tid thread performs several independent stages)
    for (int p = tid; p < 24 * H; p += 256) {
        int kk = p >> 7, c = p & 127;
        int srcrow = (kk >> 3) * 128 + (kk & 7);
        Wl[kk][c] = Ws[srcrow * H + c];
    }
    if (tid < 128) { bf2s[0][tid] = bmp[tid]; bf2s[1][tid] = bu[tid]; }
    if (tid < L1R + 1) aoff[tid] = off[r0 + tid];
    if (tid < L1R * 8) {
        int rl = tid >> 3, c = tid & 7;
        xo[rl][c] = Xo[(size_t)(r0 + rl) * FR + c];
    }
    __syncthreads();

    // phase 2: coalesced adjacency staging (contiguous CSR span)
    int abase = aoff[0];
    int acount = aoff[L1R] - abase;
    for (int i = tid; i < acount && i < AMAX; i += 256) abuf[i] = adj[abase + i];
    __syncthreads();

    // phase 3: gather (1-level chains: index from LDS, value from L2)
    {
        int rl = tid >> 4;
        int t16 = tid & 15;
        int c = t16 & 7, q = t16 >> 3;
        int b = aoff[rl] - abase + q;
        int e = aoff[rl + 1] - abase;
        float s = 0.f;
        for (int i = b; i < e; i += 2) {
            int src = (i < AMAX) ? abuf[i] : adj[abase + i];
            s += Xg[(size_t)src * FR + c];
        }
        G[rl][q][c] = s;
    }
    __syncthreads();
    if (tid < L1R * 8) {
        int rl = tid >> 3, c = tid & 7;
        S8r[rl][c] = G[rl][0][c] + G[rl][1][c];
    }
    __syncthreads();

    // phase 4: FMA, 2 rows x 4 cols per thread
    int rp = tid >> 5;          // 0..7 -> rows 2rp, 2rp+1
    int cq = tid & 31;          // 0..31 -> cols cq*4..+3
    int c0 = cq * 4;
    int ra = rp * 2, rb = ra + 1;
    float dA = deg[r0 + ra], dB = deg[r0 + rb];
    float a0[16], a1[16];
    *(float4*)(a0)     = *(const float4*)(&S8r[ra][0]);
    *(float4*)(a0 + 4) = *(const float4*)(&S8r[ra][4]);
    *(float4*)(a0 + 8) = *(const float4*)(&xo[ra][0]);
    *(float4*)(a0 + 12)= *(const float4*)(&xo[ra][4]);
    *(float4*)(a1)     = *(const float4*)(&S8r[rb][0]);
    *(float4*)(a1 + 4) = *(const float4*)(&S8r[rb][4]);
    *(float4*)(a1 + 8) = *(const float4*)(&xo[rb][0]);
    *(float4*)(a1 + 12)= *(const float4*)(&xo[rb][4]);

    float accA[4] = {}, accB[4] = {};
#pragma unroll
    for (int k = 0; k < 8; ++k) {
        float4 w = *(const float4*)(&Wl[k][c0]);
        float va = a0[k], vb = a1[k];
        accA[0] += va * w.x; accA[1] += va * w.y; accA[2] += va * w.z; accA[3] += va * w.w;
        accB[0] += vb * w.x; accB[1] += vb * w.y; accB[2] += vb * w.z; accB[3] += vb * w.w;
    }
#pragma unroll
    for (int k = 0; k < 8; ++k) {
        float4 w = *(const float4*)(&Wl[8 + k][c0]);
        float va = dA * a0[8 + k], vb = dB * a1[8 + k];
        accA[0] += va * w.x; accA[1] += va * w.y; accA[2] += va * w.z; accA[3] += va * w.w;
        accB[0] += vb * w.x; accB[1] += vb * w.y; accB[2] += vb * w.z; accB[3] += vb * w.w;
    }
#pragma unroll
    for (int k = 0; k < 8; ++k) {
        float4 w = *(const float4*)(&Wl[16 + k][c0]);
        float va = a0[8 + k], vb = a1[8 + k];
        accA[0] += va * w.x; accA[1] += va * w.y; accA[2] += va * w.z; accA[3] += va * w.w;
        accB[0] += vb * w.x; accB[1] += vb * w.y; accB[2] += vb * w.z; accB[3] += vb * w.w;
    }

    float oA[4], oB[4];
#pragma unroll
    for (int j = 0; j < 4; ++j) {
        float bm = bf2s[0][c0 + j], bb = bf2s[1][c0 + j];
        oA[j] = fmaxf(accA[j] + dA * bm + bb, 0.f);
        oB[j] = fmaxf(accB[j] + dB * bm + bb, 0.f);
    }
    *(uint2*)(Out + (size_t)(r0 + ra) * H + c0) = pk4(oA);
    *(uint2*)(Out + (size_t)(r0 + rb) * H + c0) = pk4(oB);
}

// ---------------- layer-2: fused gather + MFMA GEMM + pooled epilogue (link only) ----------------
__launch_bounds__(256)
__global__ void gemm_mfma_pool(const int* __restrict__ offL, const int* __restrict__ adjL,
                               const ushort_t* __restrict__ xlb, const ushort_t* __restrict__ xnb,
                               const float* __restrict__ dgl,
                               const ushort_t* __restrict__ WbLin, const float* __restrict__ bmpAll,
                               const float* __restrict__ bu_nl,
                               const int* __restrict__ batch, float* __restrict__ sums, int M) {
    const int* off = offL;
    const int* adj = adjL;
    const ushort_t* Xg = xnb;
    const ushort_t* Xo = xlb;
    const float* deg = dgl;
    const ushort_t* Wb = WbLin;
    const float* bmp = bmpAll + 2 * H;
    const float* bu  = bu_nl + H;

    __shared__ ushort_t T[TROWS * TSTR];   // 8.7 KB

    int tid = threadIdx.x;
    int lane = tid & 63;
    int wave = tid >> 6;
    int m0 = blockIdx.x * TROWS;
    int lrow = lane & 15, lg = lane >> 4;

    int trow = tid >> 3, chunk = tid & 7;
    int grow = m0 + trow;
    bool vr = grow < M;
    int cbase = chunk * 16;

    // ---- phase A: gather S (fp32 accum, 2-neighbor unroll) -> bf16 tile ----
    {
        float a[16];
#pragma unroll
        for (int j = 0; j < 16; ++j) a[j] = 0.f;
        if (vr) {
            int beg = off[grow], end = off[grow + 1];
            int i = beg;
            for (; i + 1 < end; i += 2) {
                const uint4* p0 = (const uint4*)(Xg + (size_t)adj[i] * H + cbase);
                const uint4* p1 = (const uint4*)(Xg + (size_t)adj[i + 1] * H + cbase);
                uint4 u0 = p0[0], u1 = p0[1];
                uint4 v0 = p1[0], v1 = p1[1];
                addpk8(a, u0); addpk8(a + 8, u1);
                addpk8(a, v0); addpk8(a + 8, v1);
            }
            if (i < end) {
                const uint4* p0 = (const uint4*)(Xg + (size_t)adj[i] * H + cbase);
                addpk8(a, p0[0]); addpk8(a + 8, p0[1]);
            }
        }
        uint4* dst = (uint4*)&T[trow * TSTR + cbase];
        uint4 w0, w1;
        unsigned* q0 = (unsigned*)&w0; unsigned* q1 = (unsigned*)&w1;
#pragma unroll
        for (int q = 0; q < 4; ++q) {
            q0[q] = (unsigned)f2bf(a[q * 2]) | ((unsigned)f2bf(a[q * 2 + 1]) << 16);
            q1[q] = (unsigned)f2bf(a[8 + q * 2]) | ((unsigned)f2bf(a[8 + q * 2 + 1]) << 16);
        }
        dst[0] = w0; dst[1] = w1;
    }

    f32x4 acc[2][2];
#pragma unroll
    for (int i = 0; i < 2; ++i)
#pragma unroll
        for (int j = 0; j < 2; ++j)
            acc[i][j] = (f32x4){0.f, 0.f, 0.f, 0.f};

    __syncthreads();
#pragma unroll
    for (int kk = 0; kk < 4; ++kk) {
        bf16x8 af[2], bfv[2];
#pragma unroll
        for (int mf = 0; mf < 2; ++mf)
            af[mf] = *(const bf16x8*)&T[(mf * 16 + lrow) * TSTR + kk * 32 + lg * 8];
#pragma unroll
        for (int nf = 0; nf < 2; ++nf)
            bfv[nf] = *(const bf16x8*)(Wb + (size_t)kk * 4096
                        + (wave * 32 + nf * 16 + lrow) * 32 + lg * 8);
#pragma unroll
        for (int mf = 0; mf < 2; ++mf)
#pragma unroll
            for (int nf = 0; nf < 2; ++nf)
                acc[mf][nf] = __builtin_amdgcn_mfma_f32_16x16x32_bf16(
                    af[mf], bfv[nf], acc[mf][nf], 0, 0, 0);
    }
    __syncthreads();

    // ---- phase B: own x row (stash) -> deg-scaled tile ----
    uint4 xs0, xs1;
    {
        if (vr) {
            const uint4* p = (const uint4*)(Xo + (size_t)grow * H + cbase);
            xs0 = p[0]; xs1 = p[1];
        } else {
            xs0 = xs1 = make_uint4(0u, 0u, 0u, 0u);
        }
        float dr = vr ? deg[grow] : 0.f;
        uint4 w0 = xs0, w1 = xs1;
        unsigned* wp0 = (unsigned*)&w0;
        unsigned* wp1 = (unsigned*)&w1;
#pragma unroll
        for (int q = 0; q < 4; ++q) {
            float v0 = dr * bf2f((ushort_t)(wp0[q] & 0xFFFF));
            float v1 = dr * bf2f((ushort_t)(wp0[q] >> 16));
            wp0[q] = (unsigned)f2bf(v0) | ((unsigned)f2bf(v1) << 16);
            float v2 = dr * bf2f((ushort_t)(wp1[q] & 0xFFFF));
            float v3 = dr * bf2f((ushort_t)(wp1[q] >> 16));
            wp1[q] = (unsigned)f2bf(v2) | ((unsigned)f2bf(v3) << 16);
        }
        uint4* dst = (uint4*)&T[trow * TSTR + cbase];
        dst[0] = w0; dst[1] = w1;
    }
    __syncthreads();
#pragma unroll
    for (int kk = 0; kk < 4; ++kk) {
        bf16x8 af[2], bfv[2];
#pragma unroll
        for (int mf = 0; mf < 2; ++mf)
            af[mf] = *(const bf16x8*)&T[(mf * 16 + lrow) * TSTR + kk * 32 + lg * 8];
#pragma unroll
        for (int nf = 0; nf < 2; ++nf)
            bfv[nf] = *(const bf16x8*)(Wb + (size_t)(4 + kk) * 4096
                        + (wave * 32 + nf * 16 + lrow) * 32 + lg * 8);
#pragma unroll
        for (int mf = 0; mf < 2; ++mf)
#pragma unroll
            for (int nf = 0; nf < 2; ++nf)
                acc[mf][nf] = __builtin_amdgcn_mfma_f32_16x16x32_bf16(
                    af[mf], bfv[nf], acc[mf][nf], 0, 0, 0);
    }
    __syncthreads();

    // ---- phase C: unscaled x tile (from stash) ----
    {
        uint4* dst = (uint4*)&T[trow * TSTR + cbase];
        dst[0] = xs0; dst[1] = xs1;
    }
    __syncthreads();
#pragma unroll
    for (int kk = 0; kk < 4; ++kk) {
        bf16x8 af[2], bfv[2];
#pragma unroll
        for (int mf = 0; mf < 2; ++mf)
            af[mf] = *(const bf16x8*)&T[(mf * 16 + lrow) * TSTR + kk * 32 + lg * 8];
#pragma unroll
        for (int nf = 0; nf < 2; ++nf)
            bfv[nf] = *(const bf16x8*)(Wb + (size_t)(8 + kk) * 4096
                        + (wave * 32 + nf * 16 + lrow) * 32 + lg * 8);
#pragma unroll
        for (int mf = 0; mf < 2; ++mf)
#pragma unroll
            for (int nf = 0; nf < 2; ++nf)
                acc[mf][nf] = __builtin_amdgcn_mfma_f32_16x16x32_bf16(
                    af[mf], bfv[nf], acc[mf][nf], 0, 0, 0);
    }

    // ---- epilogue: bias + relu + fused mean-pool ----
    float bmpv[2], buv[2];
#pragma unroll
    for (int nf = 0; nf < 2; ++nf) {
        int col = wave * 32 + nf * 16 + lrow;
        bmpv[nf] = bmp[col];
        buv[nf] = bu[col];
    }
    int lastrow = min(m0 + TROWS, M) - 1;
    int g0 = batch[m0];
    int g1 = batch[lastrow];
    if (g0 == g1) {
        float ps0 = 0.f, ps1 = 0.f;
#pragma unroll
        for (int mf = 0; mf < 2; ++mf) {
#pragma unroll
            for (int r = 0; r < 4; ++r) {
                int row = m0 + mf * 16 + lg * 4 + r;
                if (row < M) {
                    float d = deg[row];
                    ps0 += fmaxf(acc[mf][0][r] + d * bmpv[0] + buv[0], 0.f);
                    ps1 += fmaxf(acc[mf][1][r] + d * bmpv[1] + buv[1], 0.f);
                }
            }
        }
        ps0 += __shfl_xor(ps0, 16); ps0 += __shfl_xor(ps0, 32);
        ps1 += __shfl_xor(ps1, 16); ps1 += __shfl_xor(ps1, 32);
        if (lg == 0) {
            atomicAdd(&sums[g0 * H + wave * 32 + lrow], ps0);
            atomicAdd(&sums[g0 * H + wave * 32 + 16 + lrow], ps1);
        }
    } else {
#pragma unroll
        for (int mf = 0; mf < 2; ++mf) {
#pragma unroll
            for (int r = 0; r < 4; ++r) {
                int row = m0 + mf * 16 + lg * 4 + r;
                if (row < M) {
                    float d = deg[row];
                    int g = batch[row];
                    float v0 = fmaxf(acc[mf][0][r] + d * bmpv[0] + buv[0], 0.f);
                    float v1 = fmaxf(acc[mf][1][r] + d * bmpv[1] + buv[1], 0.f);
                    atomicAdd(&sums[g * H + wave * 32 + lrow], v0);
                    atomicAdd(&sums[g * H + wave * 32 + 16 + lrow], v1);
                }
            }
        }
    }
}

// ---------------- pool finalize (counts via binary search) ----------------
__global__ void pool_final(const float* __restrict__ sums, const int* __restrict__ batch,
                           float* __restrict__ out) {
    int idx = blockIdx.x * blockDim.x + threadIdx.x;
    int g = idx / H;
    int lo = 0, hi = NL;
    while (lo < hi) { int mid = (lo + hi) >> 1; if (batch[mid] < g) lo = mid + 1; else hi = mid; }
    int first = lo;
    lo = 0; hi = NL;
    while (lo < hi) { int mid = (lo + hi) >> 1; if (batch[mid] < g + 1) lo = mid + 1; else hi = mid; }
    float cnt = (float)(lo - first);
    out[idx] = sums[idx] / fmaxf(cnt, 1.f);
}

static inline size_t rup(size_t n) { return (n + 15) & ~(size_t)15; }

extern "C" void kernel_launch(void* const* d_in, const int* in_sizes, int n_in,
                              void* d_out, int out_size, void* d_ws, size_t ws_size,
                              hipStream_t stream) {
    const float* x_node = (const float*)d_in[0];
    const float* x_link = (const float*)d_in[1];
    const float* Wm_nl  = (const float*)d_in[2];
    const float* bm_nl  = (const float*)d_in[3];
    const float* Wu_nl  = (const float*)d_in[4];
    const float* bu_nl  = (const float*)d_in[5];
    const float* Wm_ln  = (const float*)d_in[6];
    const float* bm_ln  = (const float*)d_in[7];
    const float* Wu_ln  = (const float*)d_in[8];
    const float* bu_ln  = (const float*)d_in[9];
    const int* nl_edge  = (const int*)d_in[10];
    const int* ln_edge  = (const int*)d_in[11];
    const int* batch_link = (const int*)d_in[12];
    (void)in_sizes; (void)n_in; (void)out_size; (void)ws_size;

    char* wsb = (char*)d_ws;
    size_t o = 0;
    auto alloc = [&](size_t elems) { void* p = wsb + o * 4; o += rup(elems); return p; };
    ushort_t* xnb  = (ushort_t*)alloc((size_t)NN * H / 2);
    ushort_t* xlb  = (ushort_t*)alloc((size_t)NL * H / 2);
    float* deg_l = (float*)alloc(NL);
    float* deg_n = (float*)alloc(NN);
    int*   idl   = (int*)alloc(NL);
    int*   idn   = (int*)alloc(NN);
    int*   offL  = (int*)alloc(NL + 1);
    int*   offN  = (int*)alloc(NN + 1);
    int*   adjL  = (int*)alloc(NE);
    int*   adjN  = (int*)alloc(NE);
    float* Wstack= (float*)alloc(3L * 384 * H);
    float* bmp   = (float*)alloc(4 * H);
    ushort_t* WbLin = (ushort_t*)alloc(12 * 4096 / 2);
    uint_t* bbuf  = (uint_t*)alloc((size_t)2 * NB * BCAP);
    int*   bbase = (int*)alloc(2 * NB);
    float* sums  = (float*)alloc(NG * H);    // NG*H = 8192 (16-aligned)
    int*   gcount= (int*)alloc(2 * NB);      // contiguous after sums -> one memset

    hipMemsetAsync(sums, 0, ((size_t)NG * H + rup(2 * NB)) * 4, stream);

    precompute_w<<<(4 * (384 * H + H) + 255) / 256, 256, 0, stream>>>(
        Wm_nl, bm_nl, Wu_nl, Wm_ln, bm_ln, Wu_ln, Wstack, bmp, WbLin);

    // ---- CSR build ----
    bucket_scatter<<<dim3((NE + 2047) / 2048, 2), 256, 0, stream>>>(
        nl_edge, ln_edge, bbuf, gcount);
    bucket_deg2<<<dim3(NB + 1, 2), 256, 0, stream>>>(bbuf, gcount, idl, idn, bbase);
    scan_fill<<<dim3(NB, 2), 256, 0, stream>>>(
        idl, idn, bbase, offL, offN, deg_l, deg_n, bbuf, gcount, adjL, adjN);

    // ---- layer 1 (fused gather + GEMM, both relations) ----
    gemm_l1_f<<<dim3(NL / L1R, 2), 256, 0, stream>>>(
        offL, adjL, offN, adjN, x_node, x_link, deg_l, deg_n,
        Wstack, bmp, bu_nl, bu_ln, xlb, xnb);

    // ---- layer 2 (link only) + fused pool ----
    gemm_mfma_pool<<<(NL + TROWS - 1) / TROWS, 256, 0, stream>>>(
        offL, adjL, xlb, xnb, deg_l, WbLin, bmp, bu_nl,
        batch_link, sums, NL);

    pool_final<<<(NG * H) / 256, 256, 0, stream>>>(sums, batch_link, (float*)d_out);
}